// Round 1
// baseline (303.013 us; speedup 1.0000x reference)
//
#include <hip/hip_runtime.h>
#include <cstddef>

#define NTHREADS 256
#define TROW 8192
#define NROWS 512
#define TILE 1024
#define HALO 256
#define REG 1280           // region length = TILE + HALO
#define CHUNK 5            // REG / NTHREADS
#define KOUT 4             // TILE / NTHREADS
#define FEPS 1e-8f

static_assert(REG == TILE + HALO, "region");
static_assert(CHUNK * NTHREADS == REG, "chunk");
static_assert(KOUT * NTHREADS == TILE, "kout");

__device__ __forceinline__ float pow_chunk(float b) {
  // b^CHUNK with CHUNK == 5
  float b2 = b * b;
  return b2 * b2 * b;
}

// Block-wide exclusive prefix sum over REG elements (dst[0..REG], dst[0]=0).
// src(i) must be valid for i in [0, REG). Each thread owns CHUNK contiguous
// elements. Ends with __syncthreads().
template <typename SRC>
__device__ __forceinline__ void block_prefix(SRC src, float* __restrict__ dst,
                                             int tid, int lane, int wid,
                                             float* __restrict__ sc) {
  const int c0 = tid * CHUNK;
  float tot = 0.f;
#pragma unroll
  for (int k = 0; k < CHUNK; ++k) tot += src(c0 + k);
  float x = tot;
#pragma unroll
  for (int off = 1; off < 64; off <<= 1) {
    float y = __shfl_up(x, off, 64);
    if (lane >= off) x += y;
  }
  if (lane == 63) sc[wid] = x;
  __syncthreads();
  float woff = 0.f;
  for (int w = 0; w < wid; ++w) woff += sc[w];
  float run = woff + x - tot;  // exclusive prefix at chunk start
  if (tid == 0) dst[0] = 0.f;
#pragma unroll
  for (int k = 0; k < CHUNK; ++k) { run += src(c0 + k); dst[c0 + k + 1] = run; }
  __syncthreads();
}

__global__ __launch_bounds__(NTHREADS) void feat_kernel(
    const float* __restrict__ close, float* __restrict__ out) {
  __shared__ float cl[REG];
  __shared__ float Qa[REG + 1];
  __shared__ float Qb[REG + 1];
  __shared__ float sc[16];

  const int tid = threadIdx.x;
  const int lane = tid & 63;
  const int wid = tid >> 6;
  const int j = blockIdx.x;   // tile
  const int r = blockIdx.y;   // row
  const int out_start = j * TILE;
  const int s = (j == 0) ? 0 : (out_start - HALO);  // region start (global t)
  const int ob = out_start - s;                      // 0 or HALO (local out base)
  const size_t BT = (size_t)NROWS * TROW;
  const size_t rbase = (size_t)r * TROW + (size_t)s; // out index of local i=0

  // ---- P1: load region (coalesced) ----
  const float* rp = close + rbase;
#pragma unroll
  for (int k = 0; k < CHUNK; ++k) {
    int i = tid + k * NTHREADS;
    cl[i] = rp[i];
  }
  __syncthreads();
  const float c0v = cl[0];  // == close[row][0] when j==0 (pad value)

  // ---- P2: Qa = prefix(close) ----
  block_prefix([&](int i) { return cl[i]; }, Qa, tid, lane, wid, sc);

  // ---- P3: MA features (f0..f7) ----
#pragma unroll
  for (int k = 0; k < KOUT; ++k) {
    const int i = ob + tid + k * NTHREADS;
    const size_t base = rbase + (size_t)i;
    const float c = cl[i];
    const float q1 = Qa[i + 1];
#pragma unroll
    for (int wi = 0; wi < 4; ++wi) {
      const int w = (wi == 0) ? 5 : (wi == 1) ? 10 : (wi == 2) ? 20 : 50;
      const float invw = 1.f / (float)w;
      int al = i + 1 - w;
      float pad = 0.f;
      if (al < 0) { pad = (float)(-al) * c0v; al = 0; }  // only possible on tile 0
      const float ma = (q1 - Qa[al] + pad) * invw;
      out[(size_t)(2 * wi) * BT + base] = ma;
      out[(size_t)(2 * wi + 1) * BT + base] = c / (ma + FEPS);
    }
  }

  // ---- P4: Qb = prefix(sq_diff), sq_diff[i] = (close[i]-mean20[i])^2 ----
  const bool first = (j == 0);
  block_prefix(
      [&](int i) -> float {
        if (!first && i < 19) return 0.f;  // unused range for interior tiles
        int al = i - 19;
        float pad = 0.f;
        if (al < 0) { pad = (float)(-al) * c0v; al = 0; }
        const float m = (Qa[i + 1] - Qa[al] + pad) * 0.05f;
        const float d = cl[i] - m;
        return d * d;
      },
      Qb, tid, lane, wid, sc);

  // ---- P5: Bollinger (f12..f15) ----
#pragma unroll
  for (int k = 0; k < KOUT; ++k) {
    const int i = ob + tid + k * NTHREADS;
    const size_t base = rbase + (size_t)i;
    const float c = cl[i];
    int al = i - 19;
    float pad = 0.f;
    if (al < 0) { pad = (float)(-al) * c0v; al = 0; }
    const float ma20 = (Qa[i + 1] - Qa[al] + pad) * 0.05f;
    int av = i - 19;
    if (av < 0) av = 0;
    float vs = Qb[i + 1] - Qb[av];   // pad terms are (close0-mean20[0])^2 == 0
    vs = fmaxf(vs, 0.f);
    const float sd = sqrtf(vs * 0.05f + FEPS);
    const float up = ma20 + 2.f * sd;
    const float lo = ma20 - 2.f * sd;
    out[12 * BT + base] = up;
    out[13 * BT + base] = ma20;
    out[14 * BT + base] = lo;
    out[15 * BT + base] = (c - lo) / (up - lo + FEPS);
  }
  __syncthreads();  // all Qa readers done before P6 overwrites Qa

  // ---- P6: Qa = prefix(|delta|), delta[0] = 0 ----
  block_prefix(
      [&](int i) -> float { return (i == 0) ? 0.f : fabsf(cl[i] - cl[i - 1]); },
      Qa, tid, lane, wid, sc);

  // ---- P7: RSI (f8) + ATR (f16) ----
#pragma unroll
  for (int k = 0; k < KOUT; ++k) {
    const int i = ob + tid + k * NTHREADS;
    const size_t base = rbase + (size_t)i;
    const float c = cl[i];
    int ar = i - 13;
    if (ar < 0) ar = 0;
    int ap = ar - 1;
    if (ap < 0) ap = 0;
    const float sabs = Qa[i + 1] - Qa[ar];   // sum |delta| over window
    const float sdel = c - cl[ap];           // sum delta over window (telescoped)
    const float g = (sabs + sdel) * (0.5f / 14.f);
    const float l = (sabs - sdel) * (0.5f / 14.f);
    const float rs = g / (l + FEPS);
    out[8 * BT + base] = 100.f - 100.f / (1.f + rs);
    out[16 * BT + base] = sabs * (1.f / 14.f);
  }

  // ---- P8: dual EMA (12, 26) scan over cl; macd -> Qb[0..REG) ----
  {
    const float a12 = 2.f / 13.f, b12 = 11.f / 13.f;
    const float a26 = 2.f / 27.f, b26 = 25.f / 27.f;
    const int c0 = tid * CHUNK;
    float y1 = 0.f, y2 = 0.f;
#pragma unroll
    for (int k = 0; k < CHUNK; ++k) {
      const float x = cl[c0 + k];
      if (c0 + k == 0) { y1 = x; y2 = x; }      // region-start init (exact on tile 0)
      else {
        y1 = fmaf(b12, y1, a12 * x);
        y2 = fmaf(b26, y2, a26 * x);
      }
    }
    float A1 = (tid == 0) ? 0.f : pow_chunk(b12);
    float A2 = (tid == 0) ? 0.f : pow_chunk(b26);
    float B1 = y1, B2 = y2;
#pragma unroll
    for (int off = 1; off < 64; off <<= 1) {
      const float pA1 = __shfl_up(A1, off, 64), pB1 = __shfl_up(B1, off, 64);
      const float pA2 = __shfl_up(A2, off, 64), pB2 = __shfl_up(B2, off, 64);
      if (lane >= off) {
        B1 = fmaf(A1, pB1, B1); A1 *= pA1;
        B2 = fmaf(A2, pB2, B2); A2 *= pA2;
      }
    }
    float eA1 = __shfl_up(A1, 1, 64), eB1 = __shfl_up(B1, 1, 64);
    float eA2 = __shfl_up(A2, 1, 64), eB2 = __shfl_up(B2, 1, 64);
    if (lane == 0) { eA1 = 1.f; eB1 = 0.f; eA2 = 1.f; eB2 = 0.f; }
    if (lane == 63) {
      sc[wid * 4 + 0] = A1; sc[wid * 4 + 1] = B1;
      sc[wid * 4 + 2] = A2; sc[wid * 4 + 3] = B2;
    }
    __syncthreads();
    float cB1 = 0.f, cB2 = 0.f;
    for (int w = 0; w < wid; ++w) {
      cB1 = fmaf(sc[w * 4 + 0], cB1, sc[w * 4 + 1]);
      cB2 = fmaf(sc[w * 4 + 2], cB2, sc[w * 4 + 3]);
    }
    y1 = fmaf(eA1, cB1, eB1);   // carry-in for this thread's chunk
    y2 = fmaf(eA2, cB2, eB2);
#pragma unroll
    for (int k = 0; k < CHUNK; ++k) {
      const float x = cl[c0 + k];
      if (c0 + k == 0) { y1 = x; y2 = x; }
      else {
        y1 = fmaf(b12, y1, a12 * x);
        y2 = fmaf(b26, y2, a26 * x);
      }
      Qb[c0 + k] = y1 - y2;   // macd
    }
    __syncthreads();
  }

  // ---- P9: signal = ema9(macd) -> Qa[0..REG) ----
  {
    const float a9 = 0.2f, b9 = 0.8f;
    const int c0 = tid * CHUNK;
    float y = 0.f;
#pragma unroll
    for (int k = 0; k < CHUNK; ++k) {
      const float x = Qb[c0 + k];
      if (c0 + k == 0) y = x;
      else y = fmaf(b9, y, a9 * x);
    }
    float A = (tid == 0) ? 0.f : pow_chunk(b9);
    float Bv = y;
#pragma unroll
    for (int off = 1; off < 64; off <<= 1) {
      const float pA = __shfl_up(A, off, 64), pB = __shfl_up(Bv, off, 64);
      if (lane >= off) { Bv = fmaf(A, pB, Bv); A *= pA; }
    }
    float eA = __shfl_up(A, 1, 64), eB = __shfl_up(Bv, 1, 64);
    if (lane == 0) { eA = 1.f; eB = 0.f; }
    if (lane == 63) { sc[wid * 2] = A; sc[wid * 2 + 1] = Bv; }
    __syncthreads();
    float cB = 0.f;
    for (int w = 0; w < wid; ++w) cB = fmaf(sc[w * 2], cB, sc[w * 2 + 1]);
    y = fmaf(eA, cB, eB);
#pragma unroll
    for (int k = 0; k < CHUNK; ++k) {
      const float x = Qb[c0 + k];
      if (c0 + k == 0) y = x;
      else y = fmaf(b9, y, a9 * x);
      Qa[c0 + k] = y;   // signal
    }
    __syncthreads();
  }

  // ---- P10: macd (f9), signal (f10), hist (f11) ----
#pragma unroll
  for (int k = 0; k < KOUT; ++k) {
    const int i = ob + tid + k * NTHREADS;
    const size_t base = rbase + (size_t)i;
    const float m = Qb[i];
    const float sg = Qa[i];
    out[9 * BT + base] = m;
    out[10 * BT + base] = sg;
    out[11 * BT + base] = m - sg;
  }
}

extern "C" void kernel_launch(void* const* d_in, const int* in_sizes, int n_in,
                              void* d_out, int out_size, void* d_ws, size_t ws_size,
                              hipStream_t stream) {
  (void)in_sizes; (void)n_in; (void)out_size; (void)d_ws; (void)ws_size;
  const float* close = (const float*)d_in[0];  // d_in[1] = volume (unused by reference)
  float* out = (float*)d_out;
  dim3 grid(TROW / TILE, NROWS, 1);
  feat_kernel<<<grid, dim3(NTHREADS, 1, 1), 0, stream>>>(close, out);
}